// Round 1
// baseline (649.116 us; speedup 1.0000x reference)
//
#include <hip/hip_runtime.h>
#include <stdint.h>

typedef __attribute__((ext_vector_type(8))) short bf16x8;
typedef __attribute__((ext_vector_type(4))) float f32x4;

__device__ __forceinline__ float bf2f(ushort u) {
    union { uint32_t i; float f; } v; v.i = ((uint32_t)u) << 16; return v.f;
}
__device__ __forceinline__ ushort f2bf(float f) {
    union { float f; uint32_t i; } v; v.f = f;
    uint32_t r = v.i + 0x7fff + ((v.i >> 16) & 1);
    return (ushort)(r >> 16);
}

typedef unsigned int uint_as1 __attribute__((address_space(1)));
typedef unsigned int uint_as3 __attribute__((address_space(3)));
__device__ __forceinline__ void async16(const void* g, void* l) {
    __builtin_amdgcn_global_load_lds((const uint_as1*)g, (uint_as3*)l, 16, 0, 0);
}

// ---------------- small prep kernels ----------------

__global__ void cvt_f32_bf16(const float* __restrict__ in, ushort* __restrict__ out, int n) {
    int i = blockIdx.x * blockDim.x + threadIdx.x;
    if (i < n) out[i] = f2bf(in[i]);
}

__global__ void prep_bn(const float* __restrict__ bk, const float* __restrict__ gamma,
                        const float* __restrict__ beta, const float* __restrict__ rmean,
                        const float* __restrict__ rvar,
                        float* __restrict__ scaleA, float* __restrict__ shiftA) {
    int i = threadIdx.x;  // 256 threads, 1 block
    float s = gamma[i] * rsqrtf(rvar[i] + 1e-5f);
    scaleA[i] = 0.25f * s;                                // fold Ck^-0.5 = 1/16 as 0.25 per operand
    shiftA[i] = 0.25f * ((bk[i] - rmean[i]) * s + beta[i]);
}

// x [b][512][6400] f32  ->  Xt [b][6400][512] bf16
__global__ void transpose_cvt(const float* __restrict__ x, ushort* __restrict__ xt) {
    __shared__ float t[32][33];
    int b = blockIdx.z;
    int n0 = blockIdx.x * 32, c0 = blockIdx.y * 32;
    const float* xb = x + (size_t)b * 512 * 6400;
    ushort* xtb = xt + (size_t)b * 6400 * 512;
    int tx = threadIdx.x, ty = threadIdx.y;
    t[ty][tx] = xb[(size_t)(c0 + ty) * 6400 + n0 + tx];
    __syncthreads();
    xtb[(size_t)(n0 + ty) * 512 + c0 + tx] = f2bf(t[tx][ty]);
}

// ---------------- unified NT GEMM: C[i][j] = sum_k A[i][k]*B[j][k] ----------------
// EPI 0: bf16 store raw
// EPI 1: bf16 store relu(acc*vec0[col] + vec1[col])   (col-affine, BN+ReLU for Kt)
// EPI 2: bf16 store acc + vec0[row]                   (row bias, V)
// EPI 3: f32  store acc + vec0[row]                   (row bias, final out)
template <int EPI>
__global__ __launch_bounds__(256) void gemm_nt(
    const ushort* __restrict__ A, const ushort* __restrict__ B, void* __restrict__ Cout,
    int K, int lda, int ldb, int ldc,
    const float* __restrict__ vec0, const float* __restrict__ vec1) {
    __shared__ ushort lA[128 * 32];
    __shared__ ushort lB[128 * 32];

    const int tid = threadIdx.x;
    const int lane = tid & 63, wave = tid >> 6;
    const int wm = wave & 1, wn = wave >> 1;
    const int bM = blockIdx.y * 128, bN = blockIdx.x * 128;

    // staging: each wave loads 32 rows of A-tile and B-tile; one async16 = 16 rows x 32 bf16
    const int sr = lane >> 2;         // row 0..15 within 16-row group
    const int sc = (lane & 3) * 8;    // k elems 0,8,16,24
    const ushort* gA0 = A + (size_t)(bM + wave * 32 + sr) * lda + sc;
    const ushort* gA1 = gA0 + (size_t)16 * lda;
    const ushort* gB0 = B + (size_t)(bN + wave * 32 + sr) * ldb + sc;
    const ushort* gB1 = gB0 + (size_t)16 * ldb;
    ushort* lA0 = &lA[(wave * 32) * 32];
    ushort* lA1 = &lA[(wave * 32 + 16) * 32];
    ushort* lB0 = &lB[(wave * 32) * 32];
    ushort* lB1 = &lB[(wave * 32 + 16) * 32];

    const int rowA = wm * 64;          // wave's frag row base in LDS A
    const int rowB = wn * 64;
    const int fr = lane & 15;          // row within 16x16 tile
    const int fk = (lane >> 4) * 8;    // k offset within 32

    f32x4 acc[4][4] = {};

    for (int k0 = 0; k0 < K; k0 += 32) {
        async16(gA0 + k0, lA0);
        async16(gA1 + k0, lA1);
        async16(gB0 + k0, lB0);
        async16(gB1 + k0, lB1);
        __syncthreads();
        bf16x8 af[4], bff[4];
#pragma unroll
        for (int mi = 0; mi < 4; mi++)
            af[mi] = *(const bf16x8*)&lA[(rowA + mi * 16 + fr) * 32 + fk];
#pragma unroll
        for (int ni = 0; ni < 4; ni++)
            bff[ni] = *(const bf16x8*)&lB[(rowB + ni * 16 + fr) * 32 + fk];
#pragma unroll
        for (int mi = 0; mi < 4; mi++)
#pragma unroll
            for (int ni = 0; ni < 4; ni++)
                acc[mi][ni] = __builtin_amdgcn_mfma_f32_16x16x32_bf16(af[mi], bff[ni], acc[mi][ni], 0, 0, 0);
        __syncthreads();
    }

    // epilogue: D[m=(lane>>4)*4+r][n=lane&15] per 16x16 tile
    const int colb = bN + wn * 64 + (lane & 15);
    const int rowb = bM + wm * 64 + ((lane >> 4) << 2);
#pragma unroll
    for (int ni = 0; ni < 4; ni++) {
        int col = colb + ni * 16;
        float sc_ = 0.f, sh_ = 0.f;
        if (EPI == 1) { sc_ = vec0[col]; sh_ = vec1[col]; }
#pragma unroll
        for (int mi = 0; mi < 4; mi++) {
#pragma unroll
            for (int r = 0; r < 4; r++) {
                int row = rowb + mi * 16 + r;
                float v = acc[mi][ni][r];
                if (EPI == 1) v = fmaxf(v * sc_ + sh_, 0.f);
                if (EPI == 2 || EPI == 3) v += vec0[row];
                if (EPI == 3)
                    ((float*)Cout)[(size_t)row * ldc + col] = v;
                else
                    ((ushort*)Cout)[(size_t)row * ldc + col] = f2bf(v);
            }
        }
    }
}

// ---------------- softmax over rows of S (bf16 in/out, in place) ----------------
__global__ __launch_bounds__(256) void softmax_rows(ushort* __restrict__ S) {
    const int N = 6400;
    __shared__ float buf[6400];
    __shared__ float red[4];
    const int row = blockIdx.x;
    ushort* p = S + (size_t)row * N;
    const int tid = threadIdx.x;
    const int lane = tid & 63, wave = tid >> 6;

    float m = -1e30f;
    for (int i = tid; i < N; i += 256) {
        float v = bf2f(p[i]);
        buf[i] = v;
        m = fmaxf(m, v);
    }
#pragma unroll
    for (int o = 32; o > 0; o >>= 1) m = fmaxf(m, __shfl_down(m, o, 64));
    if (lane == 0) red[wave] = m;
    __syncthreads();
    float rmax = fmaxf(fmaxf(red[0], red[1]), fmaxf(red[2], red[3]));
    __syncthreads();

    float s = 0.f;
    for (int i = tid; i < N; i += 256) {
        float e = __expf(buf[i] - rmax);
        buf[i] = e;
        s += e;
    }
#pragma unroll
    for (int o = 32; o > 0; o >>= 1) s += __shfl_down(s, o, 64);
    if (lane == 0) red[wave] = s;
    __syncthreads();
    float inv = 1.f / (red[0] + red[1] + red[2] + red[3]);
    for (int i = tid; i < N; i += 256) p[i] = f2bf(buf[i] * inv);
}

// ---------------- host ----------------
extern "C" void kernel_launch(void* const* d_in, const int* in_sizes, int n_in,
                              void* d_out, int out_size, void* d_ws, size_t ws_size,
                              hipStream_t stream) {
    (void)in_sizes; (void)n_in; (void)out_size; (void)ws_size;
    const float* x     = (const float*)d_in[0];
    const float* wk    = (const float*)d_in[1];
    const float* bk    = (const float*)d_in[2];
    const float* gamma = (const float*)d_in[3];
    const float* beta  = (const float*)d_in[4];
    const float* rmean = (const float*)d_in[5];
    const float* rvar  = (const float*)d_in[6];
    const float* wv    = (const float*)d_in[7];
    const float* bv    = (const float*)d_in[8];
    const float* wW    = (const float*)d_in[9];
    const float* bW    = (const float*)d_in[10];
    float* out = (float*)d_out;

    // workspace layout (ushort elements)
    ushort* Xt   = (ushort*)d_ws;          // 2*6400*512   = 6,553,600
    ushort* wkb  = Xt + 6553600;           // 256*512      = 131,072
    ushort* wvb  = wkb + 131072;           // 131,072
    ushort* wWb  = wvb + 131072;           // 512*256      = 131,072
    ushort* Kt   = wWb + 131072;           // 2*6400*256   = 3,276,800
    ushort* V    = Kt + 3276800;           // 3,276,800
    ushort* ctxT = V + 3276800;            // 3,276,800
    ushort* S    = ctxT + 3276800;         // 6400*6400    = 40,960,000 (one batch, reused)
    float* scaleA = (float*)(S + 40960000);
    float* shiftA = scaleA + 256;
    // total ~115.5 MB

    cvt_f32_bf16<<<512, 256, 0, stream>>>(wk, wkb, 131072);
    cvt_f32_bf16<<<512, 256, 0, stream>>>(wv, wvb, 131072);
    cvt_f32_bf16<<<512, 256, 0, stream>>>(wW, wWb, 131072);
    prep_bn<<<1, 256, 0, stream>>>(bk, gamma, beta, rmean, rvar, scaleA, shiftA);
    transpose_cvt<<<dim3(200, 16, 2), dim3(32, 32), 0, stream>>>(x, Xt);

    for (int b = 0; b < 2; b++) {
        const ushort* Xtb = Xt + (size_t)b * 3276800;
        ushort* Ktb = Kt + (size_t)b * 1638400;
        ushort* Vb  = V  + (size_t)b * 1638400;
        // Kt[n][ck] = relu(affine(Xt . wk^T)), scaled by 0.25
        gemm_nt<1><<<dim3(2, 50), 256, 0, stream>>>(Xtb, wkb, Ktb, 512, 512, 512, 256, scaleA, shiftA);
        // V[v][m] = wv . Xt^T + bv
        gemm_nt<2><<<dim3(50, 2), 256, 0, stream>>>(wvb, Xtb, Vb, 512, 512, 512, 6400, bv, nullptr);
    }
    for (int b = 0; b < 2; b++) {
        ushort* Ktb  = Kt + (size_t)b * 1638400;
        ushort* Vb   = V  + (size_t)b * 1638400;
        ushort* ctxb = ctxT + (size_t)b * 1638400;
        // S[n][m] = Kt . Kt^T (already includes 1/16)
        gemm_nt<0><<<dim3(50, 50), 256, 0, stream>>>(Ktb, Ktb, S, 256, 256, 256, 6400, nullptr, nullptr);
        softmax_rows<<<6400, 256, 0, stream>>>(S);
        // ctxT[n][v] = P . V^T
        gemm_nt<0><<<dim3(2, 50), 256, 0, stream>>>(S, Vb, ctxb, 6400, 6400, 6400, 256, nullptr, nullptr);
    }
    for (int b = 0; b < 2; b++) {
        ushort* ctxb = ctxT + (size_t)b * 1638400;
        float* outb = out + (size_t)b * 3276800;
        // out[o][n] = wW . ctxT^T + bW
        gemm_nt<3><<<dim3(50, 4), 256, 0, stream>>>(wWb, ctxb, outb, 256, 256, 256, 6400, bW, nullptr);
    }
}

// Round 2
// 443.326 us; speedup vs baseline: 1.4642x; 1.4642x over previous
//
#include <hip/hip_runtime.h>
#include <stdint.h>

typedef __attribute__((ext_vector_type(8))) short bf16x8;
typedef __attribute__((ext_vector_type(4))) float f32x4;

__device__ __forceinline__ float bf2f(ushort u) {
    union { uint32_t i; float f; } v; v.i = ((uint32_t)u) << 16; return v.f;
}
__device__ __forceinline__ ushort f2bf(float f) {
    union { float f; uint32_t i; } v; v.f = f;
    uint32_t r = v.i + 0x7fff + ((v.i >> 16) & 1);
    return (ushort)(r >> 16);
}

typedef unsigned int uint_as1 __attribute__((address_space(1)));
typedef unsigned int uint_as3 __attribute__((address_space(3)));
__device__ __forceinline__ void async16(const void* g, void* l) {
    __builtin_amdgcn_global_load_lds((const uint_as1*)g, (uint_as3*)l, 16, 0, 0);
}

// ---------------- small prep kernels ----------------

__global__ void cvt_f32_bf16(const float* __restrict__ in, ushort* __restrict__ out, int n) {
    int i = blockIdx.x * blockDim.x + threadIdx.x;
    if (i < n) out[i] = f2bf(in[i]);
}

__global__ void prep_bn(const float* __restrict__ bk, const float* __restrict__ gamma,
                        const float* __restrict__ beta, const float* __restrict__ rmean,
                        const float* __restrict__ rvar,
                        float* __restrict__ scaleA, float* __restrict__ shiftA) {
    int i = threadIdx.x;  // 256 threads, 1 block
    float s = gamma[i] * rsqrtf(rvar[i] + 1e-5f);
    scaleA[i] = 0.25f * s;                                // fold Ck^-0.5 = 1/16 as 0.25 per operand
    shiftA[i] = 0.25f * ((bk[i] - rmean[i]) * s + beta[i]);
}

// x [b][512][6400] f32  ->  Xt [b][6400][512] bf16
__global__ void transpose_cvt(const float* __restrict__ x, ushort* __restrict__ xt) {
    __shared__ float t[32][33];
    int b = blockIdx.z;
    int n0 = blockIdx.x * 32, c0 = blockIdx.y * 32;
    const float* xb = x + (size_t)b * 512 * 6400;
    ushort* xtb = xt + (size_t)b * 6400 * 512;
    int tx = threadIdx.x, ty = threadIdx.y;
    t[ty][tx] = xb[(size_t)(c0 + ty) * 6400 + n0 + tx];
    __syncthreads();
    xtb[(size_t)(n0 + ty) * 512 + c0 + tx] = f2bf(t[tx][ty]);
}

// ---------------- unified NT GEMM: C[i][j] = sum_k A[i][k]*B[j][k] ----------------
// blockIdx.z applies element strides zsa/zsb/zsc to A/B/C: used for batching
// (whole-matrix strides) and for split-K (k-offset strides on A/B, chunk
// stride on C).
// EPI 0: bf16 store raw
// EPI 1: bf16 store relu(acc*vec0[col] + vec1[col])   (col-affine, BN+ReLU for Kt)
// EPI 2: bf16 store acc + vec0[row]                   (row bias, V)
// EPI 3: f32  store acc + vec0[row]                   (row bias, final out)
// EPI 4: f32  store raw                               (split-K partials)
template <int EPI>
__global__ __launch_bounds__(256) void gemm_nt(
    const ushort* __restrict__ A, const ushort* __restrict__ B, void* __restrict__ Cout,
    int K, int lda, int ldb, int ldc,
    size_t zsa, size_t zsb, size_t zsc,
    const float* __restrict__ vec0, const float* __restrict__ vec1) {
    __shared__ ushort lA[128 * 32];
    __shared__ ushort lB[128 * 32];

    A += (size_t)blockIdx.z * zsa;
    B += (size_t)blockIdx.z * zsb;

    const int tid = threadIdx.x;
    const int lane = tid & 63, wave = tid >> 6;
    const int wm = wave & 1, wn = wave >> 1;
    const int bM = blockIdx.y * 128, bN = blockIdx.x * 128;

    // staging: each wave loads 32 rows of A-tile and B-tile; one async16 = 16 rows x 32 bf16
    const int sr = lane >> 2;         // row 0..15 within 16-row group
    const int sc = (lane & 3) * 8;    // k elems 0,8,16,24
    const ushort* gA0 = A + (size_t)(bM + wave * 32 + sr) * lda + sc;
    const ushort* gA1 = gA0 + (size_t)16 * lda;
    const ushort* gB0 = B + (size_t)(bN + wave * 32 + sr) * ldb + sc;
    const ushort* gB1 = gB0 + (size_t)16 * ldb;
    ushort* lA0 = &lA[(wave * 32) * 32];
    ushort* lA1 = &lA[(wave * 32 + 16) * 32];
    ushort* lB0 = &lB[(wave * 32) * 32];
    ushort* lB1 = &lB[(wave * 32 + 16) * 32];

    const int rowA = wm * 64;          // wave's frag row base in LDS A
    const int rowB = wn * 64;
    const int fr = lane & 15;          // row within 16x16 tile
    const int fk = (lane >> 4) * 8;    // k offset within 32

    f32x4 acc[4][4] = {};

    for (int k0 = 0; k0 < K; k0 += 32) {
        async16(gA0 + k0, lA0);
        async16(gA1 + k0, lA1);
        async16(gB0 + k0, lB0);
        async16(gB1 + k0, lB1);
        __syncthreads();
        bf16x8 af[4], bff[4];
#pragma unroll
        for (int mi = 0; mi < 4; mi++)
            af[mi] = *(const bf16x8*)&lA[(rowA + mi * 16 + fr) * 32 + fk];
#pragma unroll
        for (int ni = 0; ni < 4; ni++)
            bff[ni] = *(const bf16x8*)&lB[(rowB + ni * 16 + fr) * 32 + fk];
#pragma unroll
        for (int mi = 0; mi < 4; mi++)
#pragma unroll
            for (int ni = 0; ni < 4; ni++)
                acc[mi][ni] = __builtin_amdgcn_mfma_f32_16x16x32_bf16(af[mi], bff[ni], acc[mi][ni], 0, 0, 0);
        __syncthreads();
    }

    // epilogue: D[m=(lane>>4)*4+r][n=lane&15] per 16x16 tile
    float* Cf = (float*)Cout + (size_t)blockIdx.z * zsc;
    ushort* Cu = (ushort*)Cout + (size_t)blockIdx.z * zsc;
    const int colb = bN + wn * 64 + (lane & 15);
    const int rowb = bM + wm * 64 + ((lane >> 4) << 2);
#pragma unroll
    for (int ni = 0; ni < 4; ni++) {
        int col = colb + ni * 16;
        float sc_ = 0.f, sh_ = 0.f;
        if (EPI == 1) { sc_ = vec0[col]; sh_ = vec1[col]; }
#pragma unroll
        for (int mi = 0; mi < 4; mi++) {
#pragma unroll
            for (int r = 0; r < 4; r++) {
                int row = rowb + mi * 16 + r;
                float v = acc[mi][ni][r];
                if (EPI == 1) v = fmaxf(v * sc_ + sh_, 0.f);
                if (EPI == 2 || EPI == 3) v += vec0[row];
                if (EPI == 3 || EPI == 4)
                    Cf[(size_t)row * ldc + col] = v;
                else
                    Cu[(size_t)row * ldc + col] = f2bf(v);
            }
        }
    }
}

// ---------------- split-K reduce: ctxT bf16 = sum of 4 f32 partial chunks ----------------
__global__ __launch_bounds__(256) void reduce_ctx(const float* __restrict__ part, ushort* __restrict__ ctx) {
    const size_t CH = 1638400;  // elems per chunk
    size_t i = ((size_t)blockIdx.x * 256 + threadIdx.x) * 4;
    float4 s0 = *(const float4*)&part[i];
    float4 s1 = *(const float4*)&part[i + CH];
    float4 s2 = *(const float4*)&part[i + 2 * CH];
    float4 s3 = *(const float4*)&part[i + 3 * CH];
    ushort o[4];
    o[0] = f2bf(s0.x + s1.x + s2.x + s3.x);
    o[1] = f2bf(s0.y + s1.y + s2.y + s3.y);
    o[2] = f2bf(s0.z + s1.z + s2.z + s3.z);
    o[3] = f2bf(s0.w + s1.w + s2.w + s3.w);
    *(uint2*)&ctx[i] = *(const uint2*)o;
}

// ---------------- softmax over rows of S (bf16 in/out, in place) ----------------
__global__ __launch_bounds__(256) void softmax_rows(ushort* __restrict__ S) {
    const int N = 6400;
    __shared__ float buf[6400];
    __shared__ float red[4];
    const int row = blockIdx.x;
    ushort* p = S + (size_t)row * N;
    const int tid = threadIdx.x;
    const int lane = tid & 63, wave = tid >> 6;

    float m = -1e30f;
    for (int i = tid; i < N; i += 256) {
        float v = bf2f(p[i]);
        buf[i] = v;
        m = fmaxf(m, v);
    }
#pragma unroll
    for (int o = 32; o > 0; o >>= 1) m = fmaxf(m, __shfl_down(m, o, 64));
    if (lane == 0) red[wave] = m;
    __syncthreads();
    float rmax = fmaxf(fmaxf(red[0], red[1]), fmaxf(red[2], red[3]));
    __syncthreads();

    float s = 0.f;
    for (int i = tid; i < N; i += 256) {
        float e = __expf(buf[i] - rmax);
        buf[i] = e;
        s += e;
    }
#pragma unroll
    for (int o = 32; o > 0; o >>= 1) s += __shfl_down(s, o, 64);
    if (lane == 0) red[wave] = s;
    __syncthreads();
    float inv = 1.f / (red[0] + red[1] + red[2] + red[3]);
    for (int i = tid; i < N; i += 256) p[i] = f2bf(buf[i] * inv);
}

// ---------------- host ----------------
extern "C" void kernel_launch(void* const* d_in, const int* in_sizes, int n_in,
                              void* d_out, int out_size, void* d_ws, size_t ws_size,
                              hipStream_t stream) {
    (void)in_sizes; (void)n_in; (void)out_size; (void)ws_size;
    const float* x     = (const float*)d_in[0];
    const float* wk    = (const float*)d_in[1];
    const float* bk    = (const float*)d_in[2];
    const float* gamma = (const float*)d_in[3];
    const float* beta  = (const float*)d_in[4];
    const float* rmean = (const float*)d_in[5];
    const float* rvar  = (const float*)d_in[6];
    const float* wv    = (const float*)d_in[7];
    const float* bv    = (const float*)d_in[8];
    const float* wW    = (const float*)d_in[9];
    const float* bW    = (const float*)d_in[10];
    float* out = (float*)d_out;

    // workspace layout (ushort elements)
    ushort* Xt   = (ushort*)d_ws;          // 2*6400*512   = 6,553,600
    ushort* wkb  = Xt + 6553600;           // 256*512      = 131,072
    ushort* wvb  = wkb + 131072;           // 131,072
    ushort* wWb  = wvb + 131072;           // 512*256      = 131,072
    ushort* Kt   = wWb + 131072;           // 2*6400*256   = 3,276,800
    ushort* V    = Kt + 3276800;           // 3,276,800
    ushort* ctxT = V + 3276800;            // 3,276,800
    ushort* S    = ctxT + 3276800;         // 6400*6400    = 40,960,000 (one batch, reused)
    float* scaleA = (float*)(S + 40960000);
    float* shiftA = scaleA + 256;
    float* part   = shiftA + 256;          // 4*6400*256 f32 = 6,553,600 f32 (26 MB)
    // total ~142 MB

    cvt_f32_bf16<<<512, 256, 0, stream>>>(wk, wkb, 131072);
    cvt_f32_bf16<<<512, 256, 0, stream>>>(wv, wvb, 131072);
    cvt_f32_bf16<<<512, 256, 0, stream>>>(wW, wWb, 131072);
    prep_bn<<<1, 256, 0, stream>>>(bk, gamma, beta, rmean, rvar, scaleA, shiftA);
    transpose_cvt<<<dim3(200, 16, 2), dim3(32, 32), 0, stream>>>(x, Xt);

    // Kt[b][n][ck] = relu(affine(Xt . wk^T)), scaled by 0.25  — both batches in one dispatch
    gemm_nt<1><<<dim3(2, 50, 2), 256, 0, stream>>>(Xt, wkb, Kt, 512, 512, 512, 256,
                                                   3276800, 0, 1638400, scaleA, shiftA);
    // V[b][v][m] = wv . Xt^T + bv
    gemm_nt<2><<<dim3(50, 2, 2), 256, 0, stream>>>(wvb, Xt, V, 512, 512, 512, 6400,
                                                   0, 3276800, 1638400, bv, nullptr);

    for (int b = 0; b < 2; b++) {
        ushort* Ktb  = Kt + (size_t)b * 1638400;
        ushort* Vb   = V  + (size_t)b * 1638400;
        ushort* ctxb = ctxT + (size_t)b * 1638400;
        // S[n][m] = Kt . Kt^T (already includes 1/16)
        gemm_nt<0><<<dim3(50, 50), 256, 0, stream>>>(Ktb, Ktb, S, 256, 256, 256, 6400,
                                                     0, 0, 0, nullptr, nullptr);
        softmax_rows<<<6400, 256, 0, stream>>>(S);
        // ctxT[n][v] = P . V^T — split-K x4 into f32 partials (z = k-chunk)
        gemm_nt<4><<<dim3(2, 50, 4), 256, 0, stream>>>(S, Vb, part, 1600, 6400, 6400, 256,
                                                       1600, 1600, 1638400, nullptr, nullptr);
        reduce_ctx<<<1600, 256, 0, stream>>>(part, ctxb);
    }

    // out[b][o][n] = wW . ctxT^T + bW  — both batches in one dispatch
    gemm_nt<3><<<dim3(50, 4, 2), 256, 0, stream>>>(wWb, ctxT, out, 256, 256, 256, 6400,
                                                   0, 1638400, 3276800, bW, nullptr);
}

// Round 3
// 380.916 us; speedup vs baseline: 1.7041x; 1.1638x over previous
//
#include <hip/hip_runtime.h>
#include <stdint.h>

typedef __attribute__((ext_vector_type(8))) short bf16x8;
typedef __attribute__((ext_vector_type(4))) float f32x4;

__device__ __forceinline__ float bf2f(ushort u) {
    union { uint32_t i; float f; } v; v.i = ((uint32_t)u) << 16; return v.f;
}
__device__ __forceinline__ ushort f2bf(float f) {
    union { float f; uint32_t i; } v; v.f = f;
    uint32_t r = v.i + 0x7fff + ((v.i >> 16) & 1);
    return (ushort)(r >> 16);
}
__device__ __forceinline__ void unpk(uint32_t u, float& a, float& b) {
    union { uint32_t i; float f; } x, y;
    x.i = u << 16; y.i = u & 0xffff0000u;
    a = x.f; b = y.f;
}

typedef unsigned int uint_as1 __attribute__((address_space(1)));
typedef unsigned int uint_as3 __attribute__((address_space(3)));
__device__ __forceinline__ void async16(const void* g, void* l) {
    __builtin_amdgcn_global_load_lds((const uint_as1*)g, (uint_as3*)l, 16, 0, 0);
}

// ---------------- small prep kernels ----------------

__global__ void cvt_f32_bf16(const float* __restrict__ in, ushort* __restrict__ out, int n) {
    int i = blockIdx.x * blockDim.x + threadIdx.x;
    if (i < n) out[i] = f2bf(in[i]);
}

__global__ void prep_bn(const float* __restrict__ bk, const float* __restrict__ gamma,
                        const float* __restrict__ beta, const float* __restrict__ rmean,
                        const float* __restrict__ rvar,
                        float* __restrict__ scaleA, float* __restrict__ shiftA) {
    int i = threadIdx.x;  // 256 threads, 1 block
    float s = gamma[i] * rsqrtf(rvar[i] + 1e-5f);
    scaleA[i] = 0.25f * s;                                // fold Ck^-0.5 = 1/16 as 0.25 per operand
    shiftA[i] = 0.25f * ((bk[i] - rmean[i]) * s + beta[i]);
}

// x [b][512][6400] f32  ->  Xt [b][6400][512] bf16
__global__ void transpose_cvt(const float* __restrict__ x, ushort* __restrict__ xt) {
    __shared__ float t[32][33];
    int b = blockIdx.z;
    int n0 = blockIdx.x * 32, c0 = blockIdx.y * 32;
    const float* xb = x + (size_t)b * 512 * 6400;
    ushort* xtb = xt + (size_t)b * 6400 * 512;
    int tx = threadIdx.x, ty = threadIdx.y;
    t[ty][tx] = xb[(size_t)(c0 + ty) * 6400 + n0 + tx];
    __syncthreads();
    xtb[(size_t)(n0 + ty) * 512 + c0 + tx] = f2bf(t[tx][ty]);
}

// ---------------- unified NT GEMM: C[i][j] = sum_k A[i][k]*B[j][k] ----------------
// blockIdx.z applies element strides zsa/zsb/zsc to A/B/C: used for batching
// (whole-matrix strides) and for split-K (k-offset strides on A/B, chunk
// stride on C).
// EPI 0: bf16 store raw
// EPI 1: bf16 store relu(acc*vec0[col] + vec1[col])   (col-affine, BN+ReLU for Kt)
// EPI 2: bf16 store acc + vec0[row]                   (row bias, V)
// EPI 3: f32  store acc + vec0[row]                   (row bias, final out)
// EPI 4: f32  store raw                               (split-K partials)
template <int EPI>
__global__ __launch_bounds__(256) void gemm_nt(
    const ushort* __restrict__ A, const ushort* __restrict__ B, void* __restrict__ Cout,
    int K, int lda, int ldb, int ldc,
    size_t zsa, size_t zsb, size_t zsc,
    const float* __restrict__ vec0, const float* __restrict__ vec1) {
    __shared__ ushort lA[128 * 32];
    __shared__ ushort lB[128 * 32];

    A += (size_t)blockIdx.z * zsa;
    B += (size_t)blockIdx.z * zsb;

    const int tid = threadIdx.x;
    const int lane = tid & 63, wave = tid >> 6;
    const int wm = wave & 1, wn = wave >> 1;
    const int bM = blockIdx.y * 128, bN = blockIdx.x * 128;

    // staging: each wave loads 32 rows of A-tile and B-tile; one async16 = 16 rows x 32 bf16
    const int sr = lane >> 2;         // row 0..15 within 16-row group
    const int sc = (lane & 3) * 8;    // k elems 0,8,16,24
    const ushort* gA0 = A + (size_t)(bM + wave * 32 + sr) * lda + sc;
    const ushort* gA1 = gA0 + (size_t)16 * lda;
    const ushort* gB0 = B + (size_t)(bN + wave * 32 + sr) * ldb + sc;
    const ushort* gB1 = gB0 + (size_t)16 * ldb;
    ushort* lA0 = &lA[(wave * 32) * 32];
    ushort* lA1 = &lA[(wave * 32 + 16) * 32];
    ushort* lB0 = &lB[(wave * 32) * 32];
    ushort* lB1 = &lB[(wave * 32 + 16) * 32];

    const int rowA = wm * 64;          // wave's frag row base in LDS A
    const int rowB = wn * 64;
    const int fr = lane & 15;          // row within 16x16 tile
    const int fk = (lane >> 4) * 8;    // k offset within 32

    f32x4 acc[4][4] = {};

    for (int k0 = 0; k0 < K; k0 += 32) {
        async16(gA0 + k0, lA0);
        async16(gA1 + k0, lA1);
        async16(gB0 + k0, lB0);
        async16(gB1 + k0, lB1);
        __syncthreads();
        bf16x8 af[4], bff[4];
#pragma unroll
        for (int mi = 0; mi < 4; mi++)
            af[mi] = *(const bf16x8*)&lA[(rowA + mi * 16 + fr) * 32 + fk];
#pragma unroll
        for (int ni = 0; ni < 4; ni++)
            bff[ni] = *(const bf16x8*)&lB[(rowB + ni * 16 + fr) * 32 + fk];
#pragma unroll
        for (int mi = 0; mi < 4; mi++)
#pragma unroll
            for (int ni = 0; ni < 4; ni++)
                acc[mi][ni] = __builtin_amdgcn_mfma_f32_16x16x32_bf16(af[mi], bff[ni], acc[mi][ni], 0, 0, 0);
        __syncthreads();
    }

    // epilogue: D[m=(lane>>4)*4+r][n=lane&15] per 16x16 tile
    float* Cf = (float*)Cout + (size_t)blockIdx.z * zsc;
    ushort* Cu = (ushort*)Cout + (size_t)blockIdx.z * zsc;
    const int colb = bN + wn * 64 + (lane & 15);
    const int rowb = bM + wm * 64 + ((lane >> 4) << 2);
#pragma unroll
    for (int ni = 0; ni < 4; ni++) {
        int col = colb + ni * 16;
        float sc_ = 0.f, sh_ = 0.f;
        if (EPI == 1) { sc_ = vec0[col]; sh_ = vec1[col]; }
#pragma unroll
        for (int mi = 0; mi < 4; mi++) {
#pragma unroll
            for (int r = 0; r < 4; r++) {
                int row = rowb + mi * 16 + r;
                float v = acc[mi][ni][r];
                if (EPI == 1) v = fmaxf(v * sc_ + sh_, 0.f);
                if (EPI == 2 || EPI == 3) v += vec0[row];
                if (EPI == 3 || EPI == 4)
                    Cf[(size_t)row * ldc + col] = v;
                else
                    Cu[(size_t)row * ldc + col] = f2bf(v);
            }
        }
    }
}

// ---------------- split-K reduce: ctxT bf16 = sum of 4 f32 partial chunks ----------------
__global__ __launch_bounds__(256) void reduce_ctx(const float* __restrict__ part, ushort* __restrict__ ctx) {
    const size_t CH = 1638400;  // elems per chunk
    size_t i = ((size_t)blockIdx.x * 256 + threadIdx.x) * 4;
    float4 s0 = *(const float4*)&part[i];
    float4 s1 = *(const float4*)&part[i + CH];
    float4 s2 = *(const float4*)&part[i + 2 * CH];
    float4 s3 = *(const float4*)&part[i + 3 * CH];
    ushort o[4];
    o[0] = f2bf(s0.x + s1.x + s2.x + s3.x);
    o[1] = f2bf(s0.y + s1.y + s2.y + s3.y);
    o[2] = f2bf(s0.z + s1.z + s2.z + s3.z);
    o[3] = f2bf(s0.w + s1.w + s2.w + s3.w);
    *(uint2*)&ctx[i] = *(const uint2*)o;
}

// ---------------- softmax over rows of S (bf16 in/out, in place) ----------------
// Register-resident: 800 uint4 chunks (8 bf16 each) per row; thread t owns
// chunks t, t+256, t+512, and (t<32) t+768. One global read, one write.
__global__ __launch_bounds__(256) void softmax_rows(ushort* __restrict__ S) {
    __shared__ float red[4];
    const int row = blockIdx.x;
    ushort* p = S + (size_t)row * 6400;
    const int tid = threadIdx.x;
    const int lane = tid & 63, wave = tid >> 6;
    const bool extra = tid < 32;  // chunk 768+tid

    uint4 raw[4];
    float v[32];
    float m = -1e30f;
#pragma unroll
    for (int j = 0; j < 3; j++)
        raw[j] = *(const uint4*)&p[(tid + j * 256) * 8];
    if (extra) raw[3] = *(const uint4*)&p[(tid + 768) * 8];

#pragma unroll
    for (int j = 0; j < 3; j++) {
        unpk(raw[j].x, v[j * 8 + 0], v[j * 8 + 1]);
        unpk(raw[j].y, v[j * 8 + 2], v[j * 8 + 3]);
        unpk(raw[j].z, v[j * 8 + 4], v[j * 8 + 5]);
        unpk(raw[j].w, v[j * 8 + 6], v[j * 8 + 7]);
    }
    if (extra) {
        unpk(raw[3].x, v[24], v[25]);
        unpk(raw[3].y, v[26], v[27]);
        unpk(raw[3].z, v[28], v[29]);
        unpk(raw[3].w, v[30], v[31]);
    } else {
#pragma unroll
        for (int i = 24; i < 32; i++) v[i] = -1e30f;
    }
#pragma unroll
    for (int i = 0; i < 32; i++) m = fmaxf(m, v[i]);

#pragma unroll
    for (int o = 32; o > 0; o >>= 1) m = fmaxf(m, __shfl_down(m, o, 64));
    if (lane == 0) red[wave] = m;
    __syncthreads();
    float rmax = fmaxf(fmaxf(red[0], red[1]), fmaxf(red[2], red[3]));
    __syncthreads();

    float s = 0.f;
#pragma unroll
    for (int i = 0; i < 32; i++) {
        float e = __expf(v[i] - rmax);
        v[i] = e;
        s += e;   // lanes without chunk 4 contribute exp(-1e30-rmax)=0
    }
#pragma unroll
    for (int o = 32; o > 0; o >>= 1) s += __shfl_down(s, o, 64);
    if (lane == 0) red[wave] = s;
    __syncthreads();
    float inv = 1.f / (red[0] + red[1] + red[2] + red[3]);

#pragma unroll
    for (int j = 0; j < 3; j++) {
        ushort o8[8];
#pragma unroll
        for (int e = 0; e < 8; e++) o8[e] = f2bf(v[j * 8 + e] * inv);
        *(uint4*)&p[(tid + j * 256) * 8] = *(const uint4*)o8;
    }
    if (extra) {
        ushort o8[8];
#pragma unroll
        for (int e = 0; e < 8; e++) o8[e] = f2bf(v[24 + e] * inv);
        *(uint4*)&p[(tid + 768) * 8] = *(const uint4*)o8;
    }
}

// ---------------- host ----------------
extern "C" void kernel_launch(void* const* d_in, const int* in_sizes, int n_in,
                              void* d_out, int out_size, void* d_ws, size_t ws_size,
                              hipStream_t stream) {
    (void)in_sizes; (void)n_in; (void)out_size; (void)ws_size;
    const float* x     = (const float*)d_in[0];
    const float* wk    = (const float*)d_in[1];
    const float* bk    = (const float*)d_in[2];
    const float* gamma = (const float*)d_in[3];
    const float* beta  = (const float*)d_in[4];
    const float* rmean = (const float*)d_in[5];
    const float* rvar  = (const float*)d_in[6];
    const float* wv    = (const float*)d_in[7];
    const float* bv    = (const float*)d_in[8];
    const float* wW    = (const float*)d_in[9];
    const float* bW    = (const float*)d_in[10];
    float* out = (float*)d_out;

    // workspace layout (ushort elements)
    ushort* Xt   = (ushort*)d_ws;          // 2*6400*512   = 6,553,600
    ushort* wkb  = Xt + 6553600;           // 256*512      = 131,072
    ushort* wvb  = wkb + 131072;           // 131,072
    ushort* wWb  = wvb + 131072;           // 512*256      = 131,072
    ushort* Kt   = wWb + 131072;           // 2*6400*256   = 3,276,800
    ushort* V    = Kt + 3276800;           // 3,276,800
    ushort* ctxT = V + 3276800;            // 3,276,800
    ushort* S    = ctxT + 3276800;         // 6400*6400    = 40,960,000 (one batch, reused)
    float* scaleA = (float*)(S + 40960000);
    float* shiftA = scaleA + 256;
    float* part   = shiftA + 256;          // 4*6400*256 f32 = 6,553,600 f32 (26 MB)
    // total ~142 MB

    cvt_f32_bf16<<<512, 256, 0, stream>>>(wk, wkb, 131072);
    cvt_f32_bf16<<<512, 256, 0, stream>>>(wv, wvb, 131072);
    cvt_f32_bf16<<<512, 256, 0, stream>>>(wW, wWb, 131072);
    prep_bn<<<1, 256, 0, stream>>>(bk, gamma, beta, rmean, rvar, scaleA, shiftA);
    transpose_cvt<<<dim3(200, 16, 2), dim3(32, 32), 0, stream>>>(x, Xt);

    // Kt[b][n][ck] = relu(affine(Xt . wk^T)), scaled by 0.25  — both batches in one dispatch
    gemm_nt<1><<<dim3(2, 50, 2), 256, 0, stream>>>(Xt, wkb, Kt, 512, 512, 512, 256,
                                                   3276800, 0, 1638400, scaleA, shiftA);
    // V[b][v][m] = wv . Xt^T + bv
    gemm_nt<2><<<dim3(50, 2, 2), 256, 0, stream>>>(wvb, Xt, V, 512, 512, 512, 6400,
                                                   0, 3276800, 1638400, bv, nullptr);

    for (int b = 0; b < 2; b++) {
        ushort* Ktb  = Kt + (size_t)b * 1638400;
        ushort* Vb   = V  + (size_t)b * 1638400;
        ushort* ctxb = ctxT + (size_t)b * 1638400;
        // S[n][m] = Kt . Kt^T (already includes 1/16)
        gemm_nt<0><<<dim3(50, 50), 256, 0, stream>>>(Ktb, Ktb, S, 256, 256, 256, 6400,
                                                     0, 0, 0, nullptr, nullptr);
        softmax_rows<<<6400, 256, 0, stream>>>(S);
        // ctxT[n][v] = P . V^T — split-K x4 into f32 partials (z = k-chunk)
        gemm_nt<4><<<dim3(2, 50, 4), 256, 0, stream>>>(S, Vb, part, 1600, 6400, 6400, 256,
                                                       1600, 1600, 1638400, nullptr, nullptr);
        reduce_ctx<<<1600, 256, 0, stream>>>(part, ctxb);
    }

    // out[b][o][n] = wW . ctxT^T + bW  — both batches in one dispatch
    gemm_nt<3><<<dim3(50, 4, 2), 256, 0, stream>>>(wWb, ctxT, out, 256, 256, 256, 6400,
                                                   0, 1638400, 3276800, bW, nullptr);
}